// Round 3
// baseline (262.655 us; speedup 1.0000x reference)
//
#include <hip/hip_runtime.h>
#include <stdint.h>

typedef unsigned short u16;
typedef unsigned int   u32;

#define NB   2
#define NS   2048
#define NDIM 1024
#define NH   16
#define NDH  64
// SCALE * log2(e) = 0.125 * 1.4426950408889634
#define QSCALE 0.18033688011112042f

typedef __bf16 bf16x8 __attribute__((ext_vector_type(8)));
typedef float  f32x4  __attribute__((ext_vector_type(4)));

#define MFMA_BF16(a,b,c) __builtin_amdgcn_mfma_f32_16x16x32_bf16((a),(b),(c),0,0,0)

// ---------------- ws layout (bytes) ----------------
#define XBF_OFF   (256)                          // 8 MB x bf16
#define WD_OFF    (XBF_OFF  + 8*1024*1024)       // 8 MB dense quaternion weights (q,k,v,o)
#define BIAS_OFF  (WD_OFF   + 8*1024*1024)       // 16 KB fp32 biases
#define QB_OFF    (BIAS_OFF + 16384)             // 8 MB Q (bh,s,d) bf16 (roped, pre-scaled)
#define KB_OFF    (QB_OFF   + 8*1024*1024)       // 8 MB K (bh,s,d) (roped)
#define VT_OFF    (KB_OFF   + 8*1024*1024)       // 8 MB V^T (bh,d,s)
#define OP_OFF    (VT_OFF   + 8*1024*1024)       // 16 MB O partials bf16 [split][bh][s][d]
#define LP_OFF    (OP_OFF   + 16*1024*1024)      // 512 KB l partials fp32 [split][bh][s]

__device__ __forceinline__ float bf2f(u16 h){
  union { u32 u; float f; } v; v.u = ((u32)h) << 16; return v.f;
}
__device__ __forceinline__ u16 f2bf(float f){
  union { float f; u32 u; } v; v.f = f;
  u32 r = (v.u >> 16) & 1u;
  return (u16)((v.u + 0x7fffu + r) >> 16);
}
__device__ __forceinline__ float load_val(const void* p, int i, int isbf){
  return isbf ? bf2f(((const u16*)p)[i]) : ((const float*)p)[i];
}
__device__ __forceinline__ void gl_lds16(const u16* g, u16* l){
  __builtin_amdgcn_global_load_lds(
      (__attribute__((address_space(1))) void*)(uintptr_t)g,
      (__attribute__((address_space(3))) void*)(uintptr_t)l,
      16, 0, 0);
}

// ---------------- fused prep: dtype detect + x->bf16 + weight build ----------------
// Round-8: was 3 kernels (detect, conv_x, build_w) serialized through a flag in
// global memory; each dispatch boundary costs ~10 us on this harness. Every block
// now re-derives the dtype vote locally (same 4096 u16 of x, L2-hot, deterministic),
// blocks 0..2047 additionally convert x, all 4096 blocks build weights.
struct QPtrs { const void* w[16]; const void* b[4]; };

__global__ void prep_kernel(const void* __restrict__ xin, QPtrs ptrs,
                            u16* __restrict__ xbf, u16* __restrict__ wd,
                            float* __restrict__ biasf, int* __restrict__ flag){
  __shared__ int cnt;
  if (threadIdx.x == 0) cnt = 0;
  __syncthreads();
  {
    const uint4* xv = (const uint4*)xin;
    uint4 v0 = xv[threadIdx.x * 2], v1 = xv[threadIdx.x * 2 + 1];
    const u16* hh = (const u16*)&v0;
    int ok = 0;
#pragma unroll
    for (int i = 0; i < 16; ++i){
      u16 h = (i < 8) ? hh[i] : ((const u16*)&v1)[i - 8];
      int e = (h >> 7) & 0xFF;
      if ((e > 96 && e < 158) || ((h & 0x7FFF) == 0)) ok++;
    }
    atomicAdd(&cnt, ok);
  }
  __syncthreads();
  int isbf = (cnt > 3600) ? 1 : 0;
  if (blockIdx.x == 0 && threadIdx.x == 0) *flag = isbf;

  int idx = blockIdx.x * 256 + threadIdx.x;

  // ---- conv part (blocks 0..2047 cover all 8 MB of x) ----
  if (blockIdx.x < 2048){
    int t = idx;
    if (isbf){
      ((uint4*)xbf)[t] = ((const uint4*)xin)[t];
    } else {
      const float4* f4 = (const float4*)xin;
      float4 a = f4[2*t], b = f4[2*t+1];
      ushort4 lo = { f2bf(a.x), f2bf(a.y), f2bf(a.z), f2bf(a.w) };
      ushort4 hi = { f2bf(b.x), f2bf(b.y), f2bf(b.z), f2bf(b.w) };
      ((ushort4*)xbf)[2*t]   = lo;
      ((ushort4*)xbf)[2*t+1] = hi;
    }
  }

  // ---- weight build part (all 4096 blocks) ----
  int n = idx & 255, m = (idx >> 8) & 255, c = (idx >> 16) & 3, p = idx >> 18;
  int src = m * 256 + n;
  float vr = load_val(ptrs.w[p*4+0], src, isbf);
  float vi = load_val(ptrs.w[p*4+1], src, isbf);
  float vj = load_val(ptrs.w[p*4+2], src, isbf);
  float vk = load_val(ptrs.w[p*4+3], src, isbf);
  float o0, o1, o2, o3;
  switch (c){
    case 0:  o0 = vr; o1 = -vi; o2 = -vj; o3 = -vk; break;
    case 1:  o0 = vi; o1 =  vr; o2 = -vj; o3 =  vk; break;
    case 2:  o0 = vj; o1 =  vi; o2 =  vr; o3 = -vk; break;
    default: o0 = vk; o1 = -vi; o2 =  vj; o3 =  vr; break;
  }
  ushort4 sv = { f2bf(o0), f2bf(o1), f2bf(o2), f2bf(o3) };
  *(ushort4*)&wd[(size_t)p * 1048576 + (size_t)(4*m + c) * 1024 + 4*n] = sv;
  if (idx < 4096){
    int pp = idx >> 10, oo = idx & 1023;
    biasf[idx] = load_val(ptrs.b[pp], oo, isbf);
  }
}

// ---------------- GEMM: X*Wqkv^T, fused bias+RoPE epilogue ----------------
// XOR chunk swizzle (global side) kills the 8-way fragment bank conflicts.
// Triple-buffered LDS + depth-2 prefetch + raw s_barrier with COUNTED
// s_waitcnt vmcnt(4) (round-6, verified).
__global__ __launch_bounds__(256)
void gemm_qkv_kernel(const u16* __restrict__ A, const u16* __restrict__ Bw,
                     const float* __restrict__ bias,
                     u16* __restrict__ qb, u16* __restrict__ kb, u16* __restrict__ vt){
  __shared__ u16 sA[3][128 * 32];
  __shared__ u16 sB[3][128 * 32];
  int tid = threadIdx.x, w = tid >> 6, lane = tid & 63, quad = lane >> 4, l16 = lane & 15;
  int n0 = blockIdx.x * 128, m0 = blockIdx.y * 128;

  f32x4 acc[4][4];
#pragma unroll
  for (int i = 0; i < 4; ++i)
#pragma unroll
    for (int j = 0; j < 4; ++j) acc[i][j] = (f32x4){0.f, 0.f, 0.f, 0.f};

  // staging: lane -> (row rl, chunk pos cp); fetch global chunk cp ^ ((rl>>1)&3)
  int cp = lane & 3, rl = lane >> 2;
  int gc = (cp ^ ((rl >> 1) & 3)) * 8;
  const u16* ga = A  + (size_t)(m0 + w*16 + rl) * 1024 + gc;
  const u16* gb = Bw + (size_t)(n0 + w*16 + rl) * 1024 + gc;
  int ldo = w * 512 + lane * 8;
  int xorv = ((l16 >> 1) & 3) * 8;
  int mw = (w & 1) * 64, nw = (w >> 1) * 64;

  auto stage = [&](int k0, int b){
#pragma unroll
    for (int i = 0; i < 2; ++i){
      gl_lds16(ga + (size_t)i * 65536 + k0, &sA[b][ldo + i * 2048]);
      gl_lds16(gb + (size_t)i * 65536 + k0, &sB[b][ldo + i * 2048]);
    }
  };

  stage(0, 0);
  stage(32, 1);
  asm volatile("s_waitcnt vmcnt(4)" ::: "memory");   // tile 0 landed, tile 1 in flight
  __builtin_amdgcn_s_barrier();

  int bcur = 0, bnxt = 2;   // compute buffer, stage-target buffer = (it+2)%3
  for (int it = 0; it < 32; ++it){
    if (it < 30) stage((it + 2) * 32, bnxt);
    const u16* cA = sA[bcur];
    const u16* cB = sB[bcur];
    bf16x8 af[4], bfr[4];
#pragma unroll
    for (int mt = 0; mt < 4; ++mt)
      af[mt] = *(const bf16x8*)&cA[(mw + mt*16 + l16) * 32 + (quad*8 ^ xorv)];
#pragma unroll
    for (int nt = 0; nt < 4; ++nt)
      bfr[nt] = *(const bf16x8*)&cB[(nw + nt*16 + l16) * 32 + (quad*8 ^ xorv)];
#pragma unroll
    for (int mt = 0; mt < 4; ++mt)
#pragma unroll
      for (int nt = 0; nt < 4; ++nt)
        acc[mt][nt] = MFMA_BF16(af[mt], bfr[nt], acc[mt][nt]);

    // drain stage(it+1) (needed next body); keep stage(it+2) flying
    if (it < 30) asm volatile("s_waitcnt vmcnt(4)" ::: "memory");
    else         asm volatile("s_waitcnt vmcnt(0)" ::: "memory");
    __builtin_amdgcn_s_barrier();
    bcur = (bcur == 2) ? 0 : bcur + 1;
    bnxt = (bnxt == 2) ? 0 : bnxt + 1;
  }

  int proj = n0 >> 10;    // uniform per block (proj boundary is a multiple of 128)
  if (proj == 2){
    // V^T: [bh][d][s]
#pragma unroll
    for (int mt = 0; mt < 4; ++mt){
      int row = m0 + mw + mt*16 + quad*4;
      int b = row >> 11, seq0 = row & 2047;
#pragma unroll
      for (int nt = 0; nt < 4; ++nt){
        int col = n0 + nw + nt*16 + l16;
        int o = col & 1023, h = o >> 6, d = o & 63;
        float bv = bias[col];
        ushort4 pv = { f2bf(acc[mt][nt][0] + bv), f2bf(acc[mt][nt][1] + bv),
                       f2bf(acc[mt][nt][2] + bv), f2bf(acc[mt][nt][3] + bv) };
        *(ushort4*)&vt[((size_t)((b*16 + h) * 64 + d)) * 2048 + seq0] = pv;
      }
    }
  } else {
    // Q/K with fused RoPE: out = co*v + sgn*si*partner  (partner = lane xor (ax+1))
    float sc = (proj == 0) ? QSCALE : 1.0f;
    u16* dst = proj ? kb : qb;
    int c = l16 & 3;
#pragma unroll
    for (int nt = 0; nt < 4; ++nt){
      int col = n0 + nw + nt*16 + l16;
      int o = col & 1023, h = o >> 6, d = o & 63;
      int g = d >> 2;
      int ax = g % 3;
      int mask = ax + 1;
      int tbl = (ax == 0) ? 0xA : (ax == 1 ? 0x6 : 0xC);   // '+' bits by component
      float sgn = ((tbl >> c) & 1) ? 1.f : -1.f;
      float inv = __builtin_amdgcn_exp2f(-(float)g * 0.8304820237218405f); // 10000^(-g/16)
      float bv = bias[col];
#pragma unroll
      for (int mt = 0; mt < 4; ++mt){
        int row0 = m0 + mw + mt*16 + quad*4;
        int b = row0 >> 11, s0 = row0 & 2047;
        size_t obase = ((size_t)((b*16 + h) * 2048 + s0)) * 64 + d;
#pragma unroll
        for (int r = 0; r < 4; ++r){
          float v = acc[mt][nt][r] + bv;
          float vp = __shfl_xor(v, mask);
          float ang = (float)(s0 + r) * inv;
          float co = __cosf(ang) * sc;
          float si = __sinf(ang) * sc * sgn;
          dst[obase + (size_t)r * 64] = f2bf(co * v + si * vp);
        }
      }
    }
  }
}

// ---------------- GEMM: attn partials * Wo^T -> d_out (combine fused) ----------------
// Round-8: combine_kernel eliminated. A-chunks are built in-register from the two
// split partials: a = (OP[spl0]+OP[spl1]) / (LP[spl0]+LP[spl1]), then ds_write'd
// into the swizzled LDS image (identical to what combine+gl_lds produced).
// T14 issue-early/write-late: loads for tile it+1 issue before the MFMAs of tile
// it; vmcnt(0)+convert+ds_write after. 2-buffer, full-drain __syncthreads.
__global__ __launch_bounds__(256)
void gemm_o_kernel(const u16* __restrict__ OP, const float* __restrict__ LP,
                   const u16* __restrict__ Bw, const float* __restrict__ bias,
                   void* __restrict__ dout, const int* __restrict__ flag){
  __shared__ u16 sA[2][64 * 32];
  __shared__ u16 sB[2][128 * 32];
  int tid = threadIdx.x, w = tid >> 6, lane = tid & 63, quad = lane >> 4, l16 = lane & 15;
  int n0 = blockIdx.x * 128, m0 = blockIdx.y * 64;

  f32x4 acc[2][4];
#pragma unroll
  for (int i = 0; i < 2; ++i)
#pragma unroll
    for (int j = 0; j < 4; ++j) acc[i][j] = (f32x4){0.f, 0.f, 0.f, 0.f};

  int cp = lane & 3, rl = lane >> 2;
  int gc = (cp ^ ((rl >> 1) & 3)) * 8;
  int xorv = ((l16 >> 1) & 3) * 8;
  int mw = (w & 1) * 32, nw = (w >> 1) * 64;

  // per-thread A-chunk row info (ch<4): fixed across K
  uint4 la0[3], la1[3];
  float lp0[3], lp1[3];

  auto issue_stage = [&](int k0, int b){
#pragma unroll
    for (int i = 0; i < 3; ++i){
      int ch = w * 3 + i;                 // 12 chunks: 4 A + 8 B
      int lr = (ch < 4 ? ch : ch - 4) * 16 + rl;
      if (ch < 4){
        int row = m0 + lr;
        int bb = row >> 11, ss = row & 2047;
        int c0 = k0 + gc, hh = c0 >> 6, d0 = c0 & 63;
        size_t r0 = ((size_t)(bb*16 + hh)) * 2048 + ss;
        size_t r1 = r0 + (size_t)32 * 2048;
        la0[i] = *(const uint4*)&OP[r0 * 64 + d0];
        la1[i] = *(const uint4*)&OP[r1 * 64 + d0];
        lp0[i] = LP[r0];
        lp1[i] = LP[r1];
      } else {
        int eo = (ch - 4) * 512 + lane * 8;
        gl_lds16(Bw + (size_t)(n0 + lr) * 1024 + k0 + gc, &sB[b][eo]);
      }
    }
  };
  auto write_stage = [&](int b){
#pragma unroll
    for (int i = 0; i < 3; ++i){
      int ch = w * 3 + i;
      if (ch < 4){
        int eo = ch * 512 + lane * 8;
        float il = 1.f / (lp0[i] + lp1[i]);
        const u16* h0 = (const u16*)&la0[i];
        const u16* h1 = (const u16*)&la1[i];
        union { uint4 v; u16 h[8]; } o;
#pragma unroll
        for (int j = 0; j < 8; ++j)
          o.h[j] = f2bf((bf2f(h0[j]) + bf2f(h1[j])) * il);
        *(uint4*)&sA[b][eo] = o.v;
      }
    }
  };

  issue_stage(0, 0);
  asm volatile("s_waitcnt vmcnt(0)" ::: "memory");
  write_stage(0);
  __syncthreads();

  for (int it = 0; it < 32; ++it){
    if (it < 31) issue_stage((it + 1) * 32, (it + 1) & 1);
    const u16* cA = sA[it & 1];
    const u16* cB = sB[it & 1];
    bf16x8 af[2], bfr[4];
#pragma unroll
    for (int mt = 0; mt < 2; ++mt)
      af[mt] = *(const bf16x8*)&cA[(mw + mt*16 + l16) * 32 + (quad*8 ^ xorv)];
#pragma unroll
    for (int nt = 0; nt < 4; ++nt)
      bfr[nt] = *(const bf16x8*)&cB[(nw + nt*16 + l16) * 32 + (quad*8 ^ xorv)];
#pragma unroll
    for (int mt = 0; mt < 2; ++mt)
#pragma unroll
      for (int nt = 0; nt < 4; ++nt)
        acc[mt][nt] = MFMA_BF16(af[mt], bfr[nt], acc[mt][nt]);

    if (it < 31){
      asm volatile("s_waitcnt vmcnt(0)" ::: "memory");
      write_stage((it + 1) & 1);
    }
    __syncthreads();
  }

  int isbf = *flag;
#pragma unroll
  for (int mt = 0; mt < 2; ++mt){
    int row = m0 + mw + mt*16 + quad*4;
#pragma unroll
    for (int nt = 0; nt < 4; ++nt){
      int col = n0 + nw + nt*16 + l16;
      float bv = bias[col];
#pragma unroll
      for (int r = 0; r < 4; ++r){
        float val = acc[mt][nt][r] + bv;
        size_t addr = (size_t)(row + r) * 1024 + col;
        if (isbf) ((u16*)dout)[addr] = f2bf(val);
        else      ((float*)dout)[addr] = val;
      }
    }
  }
}

// ---------------- flash attention v5: pair-balanced work assignment ----------------
// Each block runs TWO query tiles: qt = 15-z (heavy) then qt = z (light) ->
// uniform 34 half-rows/block. Grid (32,2,8) = 512 blocks, 2/CU.
#define SPT 20

__global__ __launch_bounds__(256, 2)
void attn_kernel(const u16* __restrict__ Q, const u16* __restrict__ K,
                 const u16* __restrict__ Vt, u16* __restrict__ OP,
                 float* __restrict__ LP){
  __shared__ u16 sK[2][4096];
  __shared__ u16 sPT[4][64 * SPT];
  int bh  = blockIdx.x;
  int spl = blockIdx.y;
  int tid = threadIdx.x, w = tid >> 6, lane = tid & 63, quad = lane >> 4, l16 = lane & 15;
  size_t kbase = (size_t)bh * 2048 * 64;
  size_t vbase = (size_t)bh * 64 * 2048;
  u16* spw = &sPT[w][0];

  auto stage = [&](int kt, int b){
    int kcol = kt * 64;
#pragma unroll
    for (int p = 0; p < 2; ++p){
      int slot = w*128 + p*64 + lane;
      int row = slot >> 3, dc = (slot & 7) ^ (row & 7);
      gl_lds16(K + kbase + (size_t)(kcol + row) * 64 + dc*8, &sK[b][(w*128 + p*64) * 8]);
    }
  };

  for (int item = 0; item < 2; ++item){
    int qt = item ? (int)blockIdx.z : 15 - (int)blockIdx.z;
    int rowbase = qt * 128 + w * 32;

    bf16x8 qf[2][2];
#pragma unroll
    for (int g = 0; g < 2; ++g)
#pragma unroll
      for (int kc = 0; kc < 2; ++kc)
        qf[g][kc] = *(const bf16x8*)(Q + kbase + (size_t)(rowbase + g*16 + l16) * 64 + kc*32 + quad*8);

    f32x4 oaccT[2][4];
    float lsum[2][4];
#pragma unroll
    for (int g = 0; g < 2; ++g)
#pragma unroll
      for (int i = 0; i < 4; ++i){ oaccT[g][i] = (f32x4){0.f,0.f,0.f,0.f}; lsum[g][i] = 0.f; }

    int kt0 = spl ? (qt + 1) : 0;
    int ntiles = qt + 1;

    stage(kt0, 0);
    for (int i = 0; i < ntiles; ++i){
      int kcol = (kt0 + i) * 64;
      __syncthreads();
      if (i + 1 < ntiles) stage(kt0 + i + 1, (i + 1) & 1);
      const u16* bK = sK[i & 1];

      if (kcol <= rowbase + 31){
        bf16x8 vf[4][2];
#pragma unroll
        for (int dn = 0; dn < 4; ++dn)
#pragma unroll
          for (int kc = 0; kc < 2; ++kc)
            vf[dn][kc] = *(const bf16x8*)(Vt + vbase + (size_t)(dn*16 + l16) * 2048
                                          + kcol + kc*32 + quad*8);
        bf16x8 bk[2][4];
#pragma unroll
        for (int kc = 0; kc < 2; ++kc)
#pragma unroll
          for (int nt = 0; nt < 4; ++nt){
            int rw = nt*16 + l16;
            int ch = ((kc*4 + quad) ^ (rw & 7)) * 8;
            bk[kc][nt] = *(const bf16x8*)&bK[rw*64 + ch];
          }
#pragma unroll
        for (int g = 0; g < 2; ++g){
          int G0 = rowbase + g*16;
          if (kcol <= G0 + 15){
            f32x4 sacc[4];
#pragma unroll
            for (int nt = 0; nt < 4; ++nt) sacc[nt] = (f32x4){0.f,0.f,0.f,0.f};
#pragma unroll
            for (int kc = 0; kc < 2; ++kc)
#pragma unroll
              for (int nt = 0; nt < 4; ++nt)
                sacc[nt] = MFMA_BF16(qf[g][kc], bk[kc][nt], sacc[nt]);

            if (kcol + 63 > G0){
#pragma unroll
              for (int nt = 0; nt < 4; ++nt){
                int col = kcol + nt*16 + l16;
                ushort4 pv;
#pragma unroll
                for (int r = 0; r < 4; ++r){
                  int row = G0 + quad*4 + r;
                  float pp = (col <= row) ? __builtin_amdgcn_exp2f(sacc[nt][r]) : 0.f;
                  lsum[g][r] += pp;
                  ((u16*)&pv)[r] = f2bf(pp);
                }
                *(ushort4*)&spw[(nt*16 + l16) * SPT + quad*4] = pv;
              }
            } else {
#pragma unroll
              for (int nt = 0; nt < 4; ++nt){
                ushort4 pv;
#pragma unroll
                for (int r = 0; r < 4; ++r){
                  float pp = __builtin_amdgcn_exp2f(sacc[nt][r]);
                  lsum[g][r] += pp;
                  ((u16*)&pv)[r] = f2bf(pp);
                }
                *(ushort4*)&spw[(nt*16 + l16) * SPT + quad*4] = pv;
              }
            }
#pragma unroll
            for (int kc = 0; kc < 2; ++kc){
              bf16x8 pf;
#pragma unroll
              for (int j = 0; j < 8; ++j)
                pf[j] = ((const __bf16*)spw)[(kc*32 + quad*8 + j) * SPT + l16];
#pragma unroll
              for (int dn = 0; dn < 4; ++dn)
                oaccT[g][dn] = MFMA_BF16(vf[dn][kc], pf, oaccT[g][dn]);
            }
          }
        }
      }
    }

    float* scr = (float*)spw;
#pragma unroll
    for (int g = 0; g < 2; ++g)
#pragma unroll
      for (int r = 0; r < 4; ++r){
        float l = lsum[g][r];
        l += __shfl_xor(l, 1); l += __shfl_xor(l, 2);
        l += __shfl_xor(l, 4); l += __shfl_xor(l, 8);
        if (l16 == 0) scr[g*16 + quad*4 + r] = l;
      }
    float lrow[2];
#pragma unroll
    for (int g = 0; g < 2; ++g) lrow[g] = scr[g*16 + l16];

    size_t obase = ((size_t)(spl*32 + bh)) * 2048;
#pragma unroll
    for (int g = 0; g < 2; ++g){
      int row = rowbase + g*16 + l16;
      if (quad == 0) LP[obase + row] = lrow[g];
#pragma unroll
      for (int dn = 0; dn < 4; ++dn){
        ushort4 ov = { f2bf(oaccT[g][dn][0]), f2bf(oaccT[g][dn][1]),
                       f2bf(oaccT[g][dn][2]), f2bf(oaccT[g][dn][3]) };
        *(ushort4*)&OP[(obase + row) * 64 + dn*16 + quad*4] = ov;
      }
    }

    // protect sK / sPT reuse before the second item's staging begins
    __syncthreads();
  }
}

// ---------------- launcher ----------------
extern "C" void kernel_launch(void* const* d_in, const int* in_sizes, int n_in,
                              void* d_out, int out_size, void* d_ws, size_t ws_size,
                              hipStream_t stream){
  (void)in_sizes; (void)n_in; (void)out_size; (void)ws_size;
  char* ws = (char*)d_ws;
  int*   flag  = (int*)ws;
  u16*   Xbf   = (u16*)(ws + XBF_OFF);
  u16*   Wd    = (u16*)(ws + WD_OFF);
  float* biasf = (float*)(ws + BIAS_OFF);
  u16*   Qb    = (u16*)(ws + QB_OFF);
  u16*   Kb    = (u16*)(ws + KB_OFF);
  u16*   Vt    = (u16*)(ws + VT_OFF);
  u16*   OP    = (u16*)(ws + OP_OFF);
  float* LP    = (float*)(ws + LP_OFF);

  QPtrs ptrs;
  for (int p = 0; p < 4; ++p){
    for (int wi = 0; wi < 4; ++wi) ptrs.w[p*4 + wi] = d_in[2 + p*5 + wi];
    ptrs.b[p] = d_in[2 + p*5 + 4];
  }

  prep_kernel<<<4096, 256, 0, stream>>>(d_in[0], ptrs, Xbf, Wd, biasf, flag);
  gemm_qkv_kernel<<<dim3(24, 32), 256, 0, stream>>>(Xbf, Wd, biasf, Qb, Kb, Vt);
  attn_kernel<<<dim3(32, 2, 8), 256, 0, stream>>>(Qb, Kb, Vt, OP, LP);
  gemm_o_kernel<<<dim3(8, 64), 256, 0, stream>>>(OP, LP, Wd + 3*1048576, biasf + 3072,
                                                 d_out, flag);
}

// Round 4
// 244.402 us; speedup vs baseline: 1.0747x; 1.0747x over previous
//
#include <hip/hip_runtime.h>
#include <stdint.h>

typedef unsigned short u16;
typedef unsigned int   u32;

#define NB   2
#define NS   2048
#define NDIM 1024
#define NH   16
#define NDH  64
// SCALE * log2(e) = 0.125 * 1.4426950408889634
#define QSCALE 0.18033688011112042f

typedef __bf16 bf16x8 __attribute__((ext_vector_type(8)));
typedef float  f32x4  __attribute__((ext_vector_type(4)));

#define MFMA_BF16(a,b,c) __builtin_amdgcn_mfma_f32_16x16x32_bf16((a),(b),(c),0,0,0)

// ---------------- ws layout (bytes) ----------------
#define XBF_OFF   (256)                          // 8 MB x bf16; reused as combined attention output
#define WD_OFF    (XBF_OFF  + 8*1024*1024)       // 8 MB dense quaternion weights (q,k,v,o)
#define BIAS_OFF  (WD_OFF   + 8*1024*1024)       // 16 KB fp32 biases
#define QB_OFF    (BIAS_OFF + 16384)             // 8 MB Q (bh,s,d) bf16 (roped, pre-scaled)
#define KB_OFF    (QB_OFF   + 8*1024*1024)       // 8 MB K (bh,s,d) (roped)
#define VT_OFF    (KB_OFF   + 8*1024*1024)       // 8 MB V^T (bh,d,s)
#define OP_OFF    (VT_OFF   + 8*1024*1024)       // 16 MB O partials bf16 [split][bh][s][d]
#define LP_OFF    (OP_OFF   + 16*1024*1024)      // 512 KB l partials fp32 [split][bh][s]

__device__ __forceinline__ float bf2f(u16 h){
  union { u32 u; float f; } v; v.u = ((u32)h) << 16; return v.f;
}
__device__ __forceinline__ u16 f2bf(float f){
  union { float f; u32 u; } v; v.f = f;
  u32 r = (v.u >> 16) & 1u;
  return (u16)((v.u + 0x7fffu + r) >> 16);
}
__device__ __forceinline__ float load_val(const void* p, int i, int isbf){
  return isbf ? bf2f(((const u16*)p)[i]) : ((const float*)p)[i];
}
__device__ __forceinline__ void gl_lds16(const u16* g, u16* l){
  __builtin_amdgcn_global_load_lds(
      (__attribute__((address_space(1))) void*)(uintptr_t)g,
      (__attribute__((address_space(3))) void*)(uintptr_t)l,
      16, 0, 0);
}

// ---------------- fused prep: dtype detect + x->bf16 + weight build ----------------
// Every block re-derives the dtype vote locally (same 4096 u16 of x, L2-hot,
// deterministic), blocks 0..2047 additionally convert x, all 4096 blocks build
// weights. Block 0 publishes the flag for gemm_o's epilogue.
struct QPtrs { const void* w[16]; const void* b[4]; };

__global__ void prep_kernel(const void* __restrict__ xin, QPtrs ptrs,
                            u16* __restrict__ xbf, u16* __restrict__ wd,
                            float* __restrict__ biasf, int* __restrict__ flag){
  __shared__ int cnt;
  if (threadIdx.x == 0) cnt = 0;
  __syncthreads();
  {
    const uint4* xv = (const uint4*)xin;
    uint4 v0 = xv[threadIdx.x * 2], v1 = xv[threadIdx.x * 2 + 1];
    const u16* hh = (const u16*)&v0;
    int ok = 0;
#pragma unroll
    for (int i = 0; i < 16; ++i){
      u16 h = (i < 8) ? hh[i] : ((const u16*)&v1)[i - 8];
      int e = (h >> 7) & 0xFF;
      if ((e > 96 && e < 158) || ((h & 0x7FFF) == 0)) ok++;
    }
    atomicAdd(&cnt, ok);
  }
  __syncthreads();
  int isbf = (cnt > 3600) ? 1 : 0;
  if (blockIdx.x == 0 && threadIdx.x == 0) *flag = isbf;

  int idx = blockIdx.x * 256 + threadIdx.x;

  // ---- conv part (blocks 0..2047 cover all 8 MB of x) ----
  if (blockIdx.x < 2048){
    int t = idx;
    if (isbf){
      ((uint4*)xbf)[t] = ((const uint4*)xin)[t];
    } else {
      const float4* f4 = (const float4*)xin;
      float4 a = f4[2*t], b = f4[2*t+1];
      ushort4 lo = { f2bf(a.x), f2bf(a.y), f2bf(a.z), f2bf(a.w) };
      ushort4 hi = { f2bf(b.x), f2bf(b.y), f2bf(b.z), f2bf(b.w) };
      ((ushort4*)xbf)[2*t]   = lo;
      ((ushort4*)xbf)[2*t+1] = hi;
    }
  }

  // ---- weight build part (all 4096 blocks) ----
  int n = idx & 255, m = (idx >> 8) & 255, c = (idx >> 16) & 3, p = idx >> 18;
  int src = m * 256 + n;
  float vr = load_val(ptrs.w[p*4+0], src, isbf);
  float vi = load_val(ptrs.w[p*4+1], src, isbf);
  float vj = load_val(ptrs.w[p*4+2], src, isbf);
  float vk = load_val(ptrs.w[p*4+3], src, isbf);
  float o0, o1, o2, o3;
  switch (c){
    case 0:  o0 = vr; o1 = -vi; o2 = -vj; o3 = -vk; break;
    case 1:  o0 = vi; o1 =  vr; o2 = -vj; o3 =  vk; break;
    case 2:  o0 = vj; o1 =  vi; o2 =  vr; o3 = -vk; break;
    default: o0 = vk; o1 = -vi; o2 =  vj; o3 =  vr; break;
  }
  ushort4 sv = { f2bf(o0), f2bf(o1), f2bf(o2), f2bf(o3) };
  *(ushort4*)&wd[(size_t)p * 1048576 + (size_t)(4*m + c) * 1024 + 4*n] = sv;
  if (idx < 4096){
    int pp = idx >> 10, oo = idx & 1023;
    biasf[idx] = load_val(ptrs.b[pp], oo, isbf);
  }
}

// ---------------- GEMM: X*Wqkv^T, fused bias+RoPE epilogue ----------------
// XOR chunk swizzle (global side) kills the 8-way fragment bank conflicts.
// Triple-buffered LDS + depth-2 prefetch + raw s_barrier with COUNTED
// s_waitcnt vmcnt(4) (round-6, verified).
__global__ __launch_bounds__(256)
void gemm_qkv_kernel(const u16* __restrict__ A, const u16* __restrict__ Bw,
                     const float* __restrict__ bias,
                     u16* __restrict__ qb, u16* __restrict__ kb, u16* __restrict__ vt){
  __shared__ u16 sA[3][128 * 32];
  __shared__ u16 sB[3][128 * 32];
  int tid = threadIdx.x, w = tid >> 6, lane = tid & 63, quad = lane >> 4, l16 = lane & 15;
  int n0 = blockIdx.x * 128, m0 = blockIdx.y * 128;

  f32x4 acc[4][4];
#pragma unroll
  for (int i = 0; i < 4; ++i)
#pragma unroll
    for (int j = 0; j < 4; ++j) acc[i][j] = (f32x4){0.f, 0.f, 0.f, 0.f};

  // staging: lane -> (row rl, chunk pos cp); fetch global chunk cp ^ ((rl>>1)&3)
  int cp = lane & 3, rl = lane >> 2;
  int gc = (cp ^ ((rl >> 1) & 3)) * 8;
  const u16* ga = A  + (size_t)(m0 + w*16 + rl) * 1024 + gc;
  const u16* gb = Bw + (size_t)(n0 + w*16 + rl) * 1024 + gc;
  int ldo = w * 512 + lane * 8;
  int xorv = ((l16 >> 1) & 3) * 8;
  int mw = (w & 1) * 64, nw = (w >> 1) * 64;

  auto stage = [&](int k0, int b){
#pragma unroll
    for (int i = 0; i < 2; ++i){
      gl_lds16(ga + (size_t)i * 65536 + k0, &sA[b][ldo + i * 2048]);
      gl_lds16(gb + (size_t)i * 65536 + k0, &sB[b][ldo + i * 2048]);
    }
  };

  stage(0, 0);
  stage(32, 1);
  asm volatile("s_waitcnt vmcnt(4)" ::: "memory");   // tile 0 landed, tile 1 in flight
  __builtin_amdgcn_s_barrier();

  int bcur = 0, bnxt = 2;   // compute buffer, stage-target buffer = (it+2)%3
  for (int it = 0; it < 32; ++it){
    if (it < 30) stage((it + 2) * 32, bnxt);
    const u16* cA = sA[bcur];
    const u16* cB = sB[bcur];
    bf16x8 af[4], bfr[4];
#pragma unroll
    for (int mt = 0; mt < 4; ++mt)
      af[mt] = *(const bf16x8*)&cA[(mw + mt*16 + l16) * 32 + (quad*8 ^ xorv)];
#pragma unroll
    for (int nt = 0; nt < 4; ++nt)
      bfr[nt] = *(const bf16x8*)&cB[(nw + nt*16 + l16) * 32 + (quad*8 ^ xorv)];
#pragma unroll
    for (int mt = 0; mt < 4; ++mt)
#pragma unroll
      for (int nt = 0; nt < 4; ++nt)
        acc[mt][nt] = MFMA_BF16(af[mt], bfr[nt], acc[mt][nt]);

    // drain stage(it+1) (needed next body); keep stage(it+2) flying
    if (it < 30) asm volatile("s_waitcnt vmcnt(4)" ::: "memory");
    else         asm volatile("s_waitcnt vmcnt(0)" ::: "memory");
    __builtin_amdgcn_s_barrier();
    bcur = (bcur == 2) ? 0 : bcur + 1;
    bnxt = (bnxt == 2) ? 0 : bnxt + 1;
  }

  int proj = n0 >> 10;    // uniform per block (proj boundary is a multiple of 128)
  if (proj == 2){
    // V^T: [bh][d][s]
#pragma unroll
    for (int mt = 0; mt < 4; ++mt){
      int row = m0 + mw + mt*16 + quad*4;
      int b = row >> 11, seq0 = row & 2047;
#pragma unroll
      for (int nt = 0; nt < 4; ++nt){
        int col = n0 + nw + nt*16 + l16;
        int o = col & 1023, h = o >> 6, d = o & 63;
        float bv = bias[col];
        ushort4 pv = { f2bf(acc[mt][nt][0] + bv), f2bf(acc[mt][nt][1] + bv),
                       f2bf(acc[mt][nt][2] + bv), f2bf(acc[mt][nt][3] + bv) };
        *(ushort4*)&vt[((size_t)((b*16 + h) * 64 + d)) * 2048 + seq0] = pv;
      }
    }
  } else {
    // Q/K with fused RoPE: out = co*v + sgn*si*partner  (partner = lane xor (ax+1))
    float sc = (proj == 0) ? QSCALE : 1.0f;
    u16* dst = proj ? kb : qb;
    int c = l16 & 3;
#pragma unroll
    for (int nt = 0; nt < 4; ++nt){
      int col = n0 + nw + nt*16 + l16;
      int o = col & 1023, h = o >> 6, d = o & 63;
      int g = d >> 2;
      int ax = g % 3;
      int mask = ax + 1;
      int tbl = (ax == 0) ? 0xA : (ax == 1 ? 0x6 : 0xC);   // '+' bits by component
      float sgn = ((tbl >> c) & 1) ? 1.f : -1.f;
      float inv = __builtin_amdgcn_exp2f(-(float)g * 0.8304820237218405f); // 10000^(-g/16)
      float bv = bias[col];
#pragma unroll
      for (int mt = 0; mt < 4; ++mt){
        int row0 = m0 + mw + mt*16 + quad*4;
        int b = row0 >> 11, s0 = row0 & 2047;
        size_t obase = ((size_t)((b*16 + h) * 2048 + s0)) * 64 + d;
#pragma unroll
        for (int r = 0; r < 4; ++r){
          float v = acc[mt][nt][r] + bv;
          float vp = __shfl_xor(v, mask);
          float ang = (float)(s0 + r) * inv;
          float co = __cosf(ang) * sc;
          float si = __sinf(ang) * sc * sgn;
          dst[obase + (size_t)r * 64] = f2bf(co * v + si * vp);
        }
      }
    }
  }
}

// ---------------- GEMM: attn-out * Wo^T -> d_out ----------------
// Round-4 (this round): REVERTED to the proven round-1/2 form — triple buffer,
// depth-2 prefetch, counted vmcnt(3), A from pre-combined Ab via global_load_lds.
// The round-3 fused-combine variant full-drained vmcnt(0) per K-step on scattered
// OP reads and regressed ~2x; combine goes back to its own kernel.
__global__ __launch_bounds__(256)
void gemm_o_kernel(const u16* __restrict__ A, const u16* __restrict__ Bw,
                   const float* __restrict__ bias, void* __restrict__ dout,
                   const int* __restrict__ flag){
  __shared__ u16 sA[3][64 * 32];
  __shared__ u16 sB[3][128 * 32];
  int tid = threadIdx.x, w = tid >> 6, lane = tid & 63, quad = lane >> 4, l16 = lane & 15;
  int n0 = blockIdx.x * 128, m0 = blockIdx.y * 64;

  f32x4 acc[2][4];
#pragma unroll
  for (int i = 0; i < 2; ++i)
#pragma unroll
    for (int j = 0; j < 4; ++j) acc[i][j] = (f32x4){0.f, 0.f, 0.f, 0.f};

  int cp = lane & 3, rl = lane >> 2;
  int gc = (cp ^ ((rl >> 1) & 3)) * 8;
  int xorv = ((l16 >> 1) & 3) * 8;
  int mw = (w & 1) * 32, nw = (w >> 1) * 64;

  auto stage = [&](int k0, int b){
#pragma unroll
    for (int i = 0; i < 3; ++i){
      int ch = w * 3 + i;                 // 12 chunks: 4 sA + 8 sB
      int lr = (ch < 4 ? ch : ch - 4) * 16 + rl;
      int eo = (ch < 4 ? ch : ch - 4) * 512 + lane * 8;
      if (ch < 4) gl_lds16(A  + (size_t)(m0 + lr) * 1024 + k0 + gc, &sA[b][eo]);
      else        gl_lds16(Bw + (size_t)(n0 + lr) * 1024 + k0 + gc, &sB[b][eo]);
    }
  };

  stage(0, 0);
  stage(32, 1);
  asm volatile("s_waitcnt vmcnt(3)" ::: "memory");   // tile 0 landed, tile 1 in flight
  __builtin_amdgcn_s_barrier();

  int bcur = 0, bnxt = 2;
  for (int it = 0; it < 32; ++it){
    if (it < 30) stage((it + 2) * 32, bnxt);
    const u16* cA = sA[bcur];
    const u16* cB = sB[bcur];
    bf16x8 af[2], bfr[4];
#pragma unroll
    for (int mt = 0; mt < 2; ++mt)
      af[mt] = *(const bf16x8*)&cA[(mw + mt*16 + l16) * 32 + (quad*8 ^ xorv)];
#pragma unroll
    for (int nt = 0; nt < 4; ++nt)
      bfr[nt] = *(const bf16x8*)&cB[(nw + nt*16 + l16) * 32 + (quad*8 ^ xorv)];
#pragma unroll
    for (int mt = 0; mt < 2; ++mt)
#pragma unroll
      for (int nt = 0; nt < 4; ++nt)
        acc[mt][nt] = MFMA_BF16(af[mt], bfr[nt], acc[mt][nt]);

    if (it < 30) asm volatile("s_waitcnt vmcnt(3)" ::: "memory");
    else         asm volatile("s_waitcnt vmcnt(0)" ::: "memory");
    __builtin_amdgcn_s_barrier();
    bcur = (bcur == 2) ? 0 : bcur + 1;
    bnxt = (bnxt == 2) ? 0 : bnxt + 1;
  }

  int isbf = *flag;
#pragma unroll
  for (int mt = 0; mt < 2; ++mt){
    int row = m0 + mw + mt*16 + quad*4;
#pragma unroll
    for (int nt = 0; nt < 4; ++nt){
      int col = n0 + nw + nt*16 + l16;
      float bv = bias[col];
#pragma unroll
      for (int r = 0; r < 4; ++r){
        float val = acc[mt][nt][r] + bv;
        size_t addr = (size_t)(row + r) * 1024 + col;
        if (isbf) ((u16*)dout)[addr] = f2bf(val);
        else      ((float*)dout)[addr] = val;
      }
    }
  }
}

// ---------------- flash attention v5: pair-balanced work assignment ----------------
// Each block runs TWO query tiles: qt = 15-z (heavy) then qt = z (light) ->
// uniform 34 half-rows/block. Grid (32,2,8) = 512 blocks, 2/CU.
#define SPT 20

__global__ __launch_bounds__(256, 2)
void attn_kernel(const u16* __restrict__ Q, const u16* __restrict__ K,
                 const u16* __restrict__ Vt, u16* __restrict__ OP,
                 float* __restrict__ LP){
  __shared__ u16 sK[2][4096];
  __shared__ u16 sPT[4][64 * SPT];
  int bh  = blockIdx.x;
  int spl = blockIdx.y;
  int tid = threadIdx.x, w = tid >> 6, lane = tid & 63, quad = lane >> 4, l16 = lane & 15;
  size_t kbase = (size_t)bh * 2048 * 64;
  size_t vbase = (size_t)bh * 64 * 2048;
  u16* spw = &sPT[w][0];

  auto stage = [&](int kt, int b){
    int kcol = kt * 64;
#pragma unroll
    for (int p = 0; p < 2; ++p){
      int slot = w*128 + p*64 + lane;
      int row = slot >> 3, dc = (slot & 7) ^ (row & 7);
      gl_lds16(K + kbase + (size_t)(kcol + row) * 64 + dc*8, &sK[b][(w*128 + p*64) * 8]);
    }
  };

  for (int item = 0; item < 2; ++item){
    int qt = item ? (int)blockIdx.z : 15 - (int)blockIdx.z;
    int rowbase = qt * 128 + w * 32;

    bf16x8 qf[2][2];
#pragma unroll
    for (int g = 0; g < 2; ++g)
#pragma unroll
      for (int kc = 0; kc < 2; ++kc)
        qf[g][kc] = *(const bf16x8*)(Q + kbase + (size_t)(rowbase + g*16 + l16) * 64 + kc*32 + quad*8);

    f32x4 oaccT[2][4];
    float lsum[2][4];
#pragma unroll
    for (int g = 0; g < 2; ++g)
#pragma unroll
      for (int i = 0; i < 4; ++i){ oaccT[g][i] = (f32x4){0.f,0.f,0.f,0.f}; lsum[g][i] = 0.f; }

    int kt0 = spl ? (qt + 1) : 0;
    int ntiles = qt + 1;

    stage(kt0, 0);
    for (int i = 0; i < ntiles; ++i){
      int kcol = (kt0 + i) * 64;
      __syncthreads();
      if (i + 1 < ntiles) stage(kt0 + i + 1, (i + 1) & 1);
      const u16* bK = sK[i & 1];

      if (kcol <= rowbase + 31){
        bf16x8 vf[4][2];
#pragma unroll
        for (int dn = 0; dn < 4; ++dn)
#pragma unroll
          for (int kc = 0; kc < 2; ++kc)
            vf[dn][kc] = *(const bf16x8*)(Vt + vbase + (size_t)(dn*16 + l16) * 2048
                                          + kcol + kc*32 + quad*8);
        bf16x8 bk[2][4];
#pragma unroll
        for (int kc = 0; kc < 2; ++kc)
#pragma unroll
          for (int nt = 0; nt < 4; ++nt){
            int rw = nt*16 + l16;
            int ch = ((kc*4 + quad) ^ (rw & 7)) * 8;
            bk[kc][nt] = *(const bf16x8*)&bK[rw*64 + ch];
          }
#pragma unroll
        for (int g = 0; g < 2; ++g){
          int G0 = rowbase + g*16;
          if (kcol <= G0 + 15){
            f32x4 sacc[4];
#pragma unroll
            for (int nt = 0; nt < 4; ++nt) sacc[nt] = (f32x4){0.f,0.f,0.f,0.f};
#pragma unroll
            for (int kc = 0; kc < 2; ++kc)
#pragma unroll
              for (int nt = 0; nt < 4; ++nt)
                sacc[nt] = MFMA_BF16(qf[g][kc], bk[kc][nt], sacc[nt]);

            if (kcol + 63 > G0){
#pragma unroll
              for (int nt = 0; nt < 4; ++nt){
                int col = kcol + nt*16 + l16;
                ushort4 pv;
#pragma unroll
                for (int r = 0; r < 4; ++r){
                  int row = G0 + quad*4 + r;
                  float pp = (col <= row) ? __builtin_amdgcn_exp2f(sacc[nt][r]) : 0.f;
                  lsum[g][r] += pp;
                  ((u16*)&pv)[r] = f2bf(pp);
                }
                *(ushort4*)&spw[(nt*16 + l16) * SPT + quad*4] = pv;
              }
            } else {
#pragma unroll
              for (int nt = 0; nt < 4; ++nt){
                ushort4 pv;
#pragma unroll
                for (int r = 0; r < 4; ++r){
                  float pp = __builtin_amdgcn_exp2f(sacc[nt][r]);
                  lsum[g][r] += pp;
                  ((u16*)&pv)[r] = f2bf(pp);
                }
                *(ushort4*)&spw[(nt*16 + l16) * SPT + quad*4] = pv;
              }
            }
#pragma unroll
            for (int kc = 0; kc < 2; ++kc){
              bf16x8 pf;
#pragma unroll
              for (int j = 0; j < 8; ++j)
                pf[j] = ((const __bf16*)spw)[(kc*32 + quad*8 + j) * SPT + l16];
#pragma unroll
              for (int dn = 0; dn < 4; ++dn)
                oaccT[g][dn] = MFMA_BF16(vf[dn][kc], pf, oaccT[g][dn]);
            }
          }
        }
      }
    }

    float* scr = (float*)spw;
#pragma unroll
    for (int g = 0; g < 2; ++g)
#pragma unroll
      for (int r = 0; r < 4; ++r){
        float l = lsum[g][r];
        l += __shfl_xor(l, 1); l += __shfl_xor(l, 2);
        l += __shfl_xor(l, 4); l += __shfl_xor(l, 8);
        if (l16 == 0) scr[g*16 + quad*4 + r] = l;
      }
    float lrow[2];
#pragma unroll
    for (int g = 0; g < 2; ++g) lrow[g] = scr[g*16 + l16];

    size_t obase = ((size_t)(spl*32 + bh)) * 2048;
#pragma unroll
    for (int g = 0; g < 2; ++g){
      int row = rowbase + g*16 + l16;
      if (quad == 0) LP[obase + row] = lrow[g];
#pragma unroll
      for (int dn = 0; dn < 4; ++dn){
        ushort4 ov = { f2bf(oaccT[g][dn][0]), f2bf(oaccT[g][dn][1]),
                       f2bf(oaccT[g][dn][2]), f2bf(oaccT[g][dn][3]) };
        *(ushort4*)&OP[(obase + row) * 64 + dn*16 + quad*4] = ov;
      }
    }

    // protect sK / sPT reuse before the second item's staging begins
    __syncthreads();
  }
}

// ---------------- combine splits -> Ab (b, s, h*64+d) bf16 ----------------
__global__ void combine_kernel(const u16* __restrict__ OP, const float* __restrict__ LP,
                               u16* __restrict__ Ab){
  int idx = blockIdx.x * 256 + threadIdx.x;
  int dc = idx & 7, s = (idx >> 3) & 2047, bh = idx >> 14;
  size_t r0 = (size_t)bh * 2048 + s, r1 = (size_t)(32 + bh) * 2048 + s;
  float invl = 1.f / (LP[r0] + LP[r1]);
  union { uint4 v; u16 h[8]; } a0, a1; ushort4 o[2];
  a0.v = *(const uint4*)&OP[r0 * 64 + dc*8];
  a1.v = *(const uint4*)&OP[r1 * 64 + dc*8];
#pragma unroll
  for (int p = 0; p < 2; ++p)
#pragma unroll
    for (int j = 0; j < 4; ++j)
      ((u16*)&o[p])[j] = f2bf((bf2f(a0.h[p*4+j]) + bf2f(a1.h[p*4+j])) * invl);
  int b = bh >> 4, h = bh & 15;
  u16* dst = &Ab[((size_t)(b*2048 + s)) * 1024 + h*64 + dc*8];
  *(ushort4*)dst = o[0];
  *(ushort4*)(dst + 4) = o[1];
}

// ---------------- launcher ----------------
extern "C" void kernel_launch(void* const* d_in, const int* in_sizes, int n_in,
                              void* d_out, int out_size, void* d_ws, size_t ws_size,
                              hipStream_t stream){
  (void)in_sizes; (void)n_in; (void)out_size; (void)ws_size;
  char* ws = (char*)d_ws;
  int*   flag  = (int*)ws;
  u16*   Xbf   = (u16*)(ws + XBF_OFF);
  u16*   Wd    = (u16*)(ws + WD_OFF);
  float* biasf = (float*)(ws + BIAS_OFF);
  u16*   Qb    = (u16*)(ws + QB_OFF);
  u16*   Kb    = (u16*)(ws + KB_OFF);
  u16*   Vt    = (u16*)(ws + VT_OFF);
  u16*   OP    = (u16*)(ws + OP_OFF);
  float* LP    = (float*)(ws + LP_OFF);
  u16*   Ab    = Xbf;

  QPtrs ptrs;
  for (int p = 0; p < 4; ++p){
    for (int wi = 0; wi < 4; ++wi) ptrs.w[p*4 + wi] = d_in[2 + p*5 + wi];
    ptrs.b[p] = d_in[2 + p*5 + 4];
  }

  prep_kernel<<<4096, 256, 0, stream>>>(d_in[0], ptrs, Xbf, Wd, biasf, flag);
  gemm_qkv_kernel<<<dim3(24, 32), 256, 0, stream>>>(Xbf, Wd, biasf, Qb, Kb, Vt);
  attn_kernel<<<dim3(32, 2, 8), 256, 0, stream>>>(Qb, Kb, Vt, OP, LP);
  combine_kernel<<<2048, 256, 0, stream>>>(OP, LP, Ab);
  gemm_o_kernel<<<dim3(8, 64), 256, 0, stream>>>(Ab, Wd + 3*1048576, biasf + 3072,
                                                 d_out, flag);
}

// Round 5
// 241.649 us; speedup vs baseline: 1.0869x; 1.0114x over previous
//
#include <hip/hip_runtime.h>
#include <stdint.h>

typedef unsigned short u16;
typedef unsigned int   u32;

#define NB   2
#define NS   2048
#define NDIM 1024
#define NH   16
#define NDH  64
// SCALE * log2(e) = 0.125 * 1.4426950408889634
#define QSCALE 0.18033688011112042f

typedef __bf16 bf16x8 __attribute__((ext_vector_type(8)));
typedef float  f32x4  __attribute__((ext_vector_type(4)));

#define MFMA_BF16(a,b,c) __builtin_amdgcn_mfma_f32_16x16x32_bf16((a),(b),(c),0,0,0)

// ---------------- ws layout (bytes) ----------------
#define XBF_OFF   (256)                          // 8 MB x bf16; reused as combined attention output
#define WD_OFF    (XBF_OFF  + 8*1024*1024)       // 8 MB dense quaternion weights (q,k,v,o)
#define BIAS_OFF  (WD_OFF   + 8*1024*1024)       // 16 KB fp32 biases
#define QB_OFF    (BIAS_OFF + 16384)             // 8 MB Q (bh,s,d) bf16 (roped, pre-scaled)
#define KB_OFF    (QB_OFF   + 8*1024*1024)       // 8 MB K (bh,s,d) (roped)
#define VT_OFF    (KB_OFF   + 8*1024*1024)       // 8 MB V^T (bh,d,s)
#define OP_OFF    (VT_OFF   + 8*1024*1024)       // 16 MB O partials bf16 [split][bh][s][d]
#define LP_OFF    (OP_OFF   + 16*1024*1024)      // 512 KB l partials fp32 [split][bh][s]

__device__ __forceinline__ float bf2f(u16 h){
  union { u32 u; float f; } v; v.u = ((u32)h) << 16; return v.f;
}
__device__ __forceinline__ u16 f2bf(float f){
  union { float f; u32 u; } v; v.f = f;
  u32 r = (v.u >> 16) & 1u;
  return (u16)((v.u + 0x7fffu + r) >> 16);
}
__device__ __forceinline__ float load_val(const void* p, int i, int isbf){
  return isbf ? bf2f(((const u16*)p)[i]) : ((const float*)p)[i];
}
__device__ __forceinline__ void gl_lds16(const u16* g, u16* l){
  __builtin_amdgcn_global_load_lds(
      (__attribute__((address_space(1))) void*)(uintptr_t)g,
      (__attribute__((address_space(3))) void*)(uintptr_t)l,
      16, 0, 0);
}

// ---------------- fused prep: dtype detect + x->bf16 + weight build ----------------
struct QPtrs { const void* w[16]; const void* b[4]; };

__global__ void prep_kernel(const void* __restrict__ xin, QPtrs ptrs,
                            u16* __restrict__ xbf, u16* __restrict__ wd,
                            float* __restrict__ biasf, int* __restrict__ flag){
  __shared__ int cnt;
  if (threadIdx.x == 0) cnt = 0;
  __syncthreads();
  {
    const uint4* xv = (const uint4*)xin;
    uint4 v0 = xv[threadIdx.x * 2], v1 = xv[threadIdx.x * 2 + 1];
    const u16* hh = (const u16*)&v0;
    int ok = 0;
#pragma unroll
    for (int i = 0; i < 16; ++i){
      u16 h = (i < 8) ? hh[i] : ((const u16*)&v1)[i - 8];
      int e = (h >> 7) & 0xFF;
      if ((e > 96 && e < 158) || ((h & 0x7FFF) == 0)) ok++;
    }
    atomicAdd(&cnt, ok);
  }
  __syncthreads();
  int isbf = (cnt > 3600) ? 1 : 0;
  if (blockIdx.x == 0 && threadIdx.x == 0) *flag = isbf;

  int idx = blockIdx.x * 256 + threadIdx.x;

  // ---- conv part (blocks 0..2047 cover all 8 MB of x) ----
  if (blockIdx.x < 2048){
    int t = idx;
    if (isbf){
      ((uint4*)xbf)[t] = ((const uint4*)xin)[t];
    } else {
      const float4* f4 = (const float4*)xin;
      float4 a = f4[2*t], b = f4[2*t+1];
      ushort4 lo = { f2bf(a.x), f2bf(a.y), f2bf(a.z), f2bf(a.w) };
      ushort4 hi = { f2bf(b.x), f2bf(b.y), f2bf(b.z), f2bf(b.w) };
      ((ushort4*)xbf)[2*t]   = lo;
      ((ushort4*)xbf)[2*t+1] = hi;
    }
  }

  // ---- weight build part (all 4096 blocks) ----
  int n = idx & 255, m = (idx >> 8) & 255, c = (idx >> 16) & 3, p = idx >> 18;
  int src = m * 256 + n;
  float vr = load_val(ptrs.w[p*4+0], src, isbf);
  float vi = load_val(ptrs.w[p*4+1], src, isbf);
  float vj = load_val(ptrs.w[p*4+2], src, isbf);
  float vk = load_val(ptrs.w[p*4+3], src, isbf);
  float o0, o1, o2, o3;
  switch (c){
    case 0:  o0 = vr; o1 = -vi; o2 = -vj; o3 = -vk; break;
    case 1:  o0 = vi; o1 =  vr; o2 = -vj; o3 =  vk; break;
    case 2:  o0 = vj; o1 =  vi; o2 =  vr; o3 = -vk; break;
    default: o0 = vk; o1 = -vi; o2 =  vj; o3 =  vr; break;
  }
  ushort4 sv = { f2bf(o0), f2bf(o1), f2bf(o2), f2bf(o3) };
  *(ushort4*)&wd[(size_t)p * 1048576 + (size_t)(4*m + c) * 1024 + 4*n] = sv;
  if (idx < 4096){
    int pp = idx >> 10, oo = idx & 1023;
    biasf[idx] = load_val(ptrs.b[pp], oo, isbf);
  }
}

// ---------------- GEMM: X*Wqkv^T, 256x256 8-wave, fused bias+RoPE epilogue ----------------
// Round-9: ported to the 256^2 structure (T2+T3+T4+T5). 512 threads = 8 waves
// (2M x 4N), per-wave output 128x64 (acc[8][4]). BK=32, 3 LDS buffers (96 KB),
// depth-2 prefetch, counted s_waitcnt vmcnt(4) once per K-tile (never 0 in
// steady state). Each K-tile runs 2 lock-step phases: {issue 2 global_load_lds,
// 8 ds_read_b128, lgkmcnt(0)+sched_barrier, setprio(1), 16 MFMA, setprio(0),
// s_barrier}. Addressing idioms (chunk-XOR swizzle (l16>>1)&3, pre-swizzled
// global source + linear LDS dest) carried over unchanged from the proven 128^2
// kernel. Correctness of buffer rotation: tile t reads buf t%3; stage target of
// t+2 is (t+2)%3 != t%3, (t+1)%3 -> never overwrites a live buffer.
__global__ __launch_bounds__(512, 2)
void gemm_qkv_kernel(const u16* __restrict__ A, const u16* __restrict__ Bw,
                     const float* __restrict__ bias,
                     u16* __restrict__ qb, u16* __restrict__ kb, u16* __restrict__ vt){
  __shared__ u16 sA[3][256 * 32];
  __shared__ u16 sB[3][256 * 32];
  int tid = threadIdx.x, lane = tid & 63, quad = lane >> 4, l16 = lane & 15;
  int wid = tid >> 6;
  int wr = wid >> 2, wc = wid & 3;            // wave grid 2M x 4N
  int mbase = wr * 128, nbase = wc * 64;
  int n0 = blockIdx.x * 256, m0 = blockIdx.y * 256;

  f32x4 acc[8][4];
#pragma unroll
  for (int i = 0; i < 8; ++i)
#pragma unroll
    for (int j = 0; j < 4; ++j) acc[i][j] = (f32x4){0.f, 0.f, 0.f, 0.f};

  // ---- staging: thread t covers chunk ids {t, t+512} of each 256x32 tile ----
  // chunk id -> row = cid>>2, linear chunk col = cid&3; global fetch col is
  // XOR-swizzled: cg = cl ^ ((row>>1)&3). LDS stays linear (gl_lds requirement).
  const u16* gA = A  + (size_t)m0 * 1024;
  const u16* gB = Bw + (size_t)n0 * 1024;
  int r0s = tid >> 2,            c0s = tid & 3;
  int r1s = (tid + 512) >> 2,    c1s = (tid + 512) & 3;
  int sa0 = r0s * 1024 + (c0s ^ ((r0s >> 1) & 3)) * 8;
  int sa1 = r1s * 1024 + (c1s ^ ((r1s >> 1) & 3)) * 8;
  int d0 = tid * 8, d1 = (tid + 512) * 8;

  auto stage_A = [&](int t, int b){
    int k0 = t * 32;
    gl_lds16(gA + sa0 + k0, &sA[b][d0]);
    gl_lds16(gA + sa1 + k0, &sA[b][d1]);
  };
  auto stage_B = [&](int t, int b){
    int k0 = t * 32;
    gl_lds16(gB + sa0 + k0, &sB[b][d0]);
    gl_lds16(gB + sa1 + k0, &sB[b][d1]);
  };

  // fragment-read chunk offset: (quad ^ ((l16>>1)&3)) * 8  (2-way conflict, free)
  int xo = (quad ^ ((l16 >> 1) & 3)) * 8;

  stage_A(0, 0); stage_B(0, 0);
  stage_A(1, 1); stage_B(1, 1);
  asm volatile("s_waitcnt vmcnt(4)" ::: "memory");   // tile 0 landed, tile 1 in flight
  __builtin_amdgcn_s_barrier();

  int bcur = 0, bst = 2;
  for (int t = 0; t < 32; ++t){
    const u16* cA = sA[bcur];
    const u16* cB = sB[bcur];

    // ---- phase 0: mt 0..3 ----
    if (t < 30) stage_A(t + 2, bst);
    {
      bf16x8 af[4], bfr[4];
#pragma unroll
      for (int mt = 0; mt < 4; ++mt)
        af[mt] = *(const bf16x8*)&cA[(mbase + mt*16 + l16) * 32 + xo];
#pragma unroll
      for (int nt = 0; nt < 4; ++nt)
        bfr[nt] = *(const bf16x8*)&cB[(nbase + nt*16 + l16) * 32 + xo];
      asm volatile("s_waitcnt lgkmcnt(0)" ::: "memory");
      __builtin_amdgcn_sched_barrier(0);
      __builtin_amdgcn_s_setprio(1);
#pragma unroll
      for (int mt = 0; mt < 4; ++mt)
#pragma unroll
        for (int nt = 0; nt < 4; ++nt)
          acc[mt][nt] = MFMA_BF16(af[mt], bfr[nt], acc[mt][nt]);
      __builtin_amdgcn_s_setprio(0);
    }
    __builtin_amdgcn_s_barrier();

    // ---- phase 1: mt 4..7 ----
    if (t < 30) stage_B(t + 2, bst);
    {
      bf16x8 af[4], bfr[4];
#pragma unroll
      for (int mt = 0; mt < 4; ++mt)
        af[mt] = *(const bf16x8*)&cA[(mbase + (4+mt)*16 + l16) * 32 + xo];
#pragma unroll
      for (int nt = 0; nt < 4; ++nt)
        bfr[nt] = *(const bf16x8*)&cB[(nbase + nt*16 + l16) * 32 + xo];
      asm volatile("s_waitcnt lgkmcnt(0)" ::: "memory");
      __builtin_amdgcn_sched_barrier(0);
      __builtin_amdgcn_s_setprio(1);
#pragma unroll
      for (int mt = 0; mt < 4; ++mt)
#pragma unroll
        for (int nt = 0; nt < 4; ++nt)
          acc[4+mt][nt] = MFMA_BF16(af[mt], bfr[nt], acc[4+mt][nt]);
      __builtin_amdgcn_s_setprio(0);
    }
    if (t < 31){
      // drain tile t+1 (needed next); keep tile t+2's 4 loads flying
      if (t < 30) asm volatile("s_waitcnt vmcnt(4)" ::: "memory");
      else        asm volatile("s_waitcnt vmcnt(0)" ::: "memory");
      __builtin_amdgcn_s_barrier();
    }
    bcur = (bcur == 2) ? 0 : bcur + 1;
    bst  = (bst  == 2) ? 0 : bst  + 1;
  }

  int proj = n0 >> 10;    // uniform per block (256 divides the 1024 proj boundary)
  if (proj == 2){
    // V^T: [bh][d][s]
#pragma unroll
    for (int mt = 0; mt < 8; ++mt){
      int row = m0 + mbase + mt*16 + quad*4;
      int b = row >> 11, seq0 = row & 2047;
#pragma unroll
      for (int nt = 0; nt < 4; ++nt){
        int col = n0 + nbase + nt*16 + l16;
        int o = col & 1023, h = o >> 6, d = o & 63;
        float bv = bias[col];
        ushort4 pv = { f2bf(acc[mt][nt][0] + bv), f2bf(acc[mt][nt][1] + bv),
                       f2bf(acc[mt][nt][2] + bv), f2bf(acc[mt][nt][3] + bv) };
        *(ushort4*)&vt[((size_t)((b*16 + h) * 64 + d)) * 2048 + seq0] = pv;
      }
    }
  } else {
    // Q/K with fused RoPE: out = co*v + sgn*si*partner  (partner = lane xor (ax+1))
    float sc = (proj == 0) ? QSCALE : 1.0f;
    u16* dst = proj ? kb : qb;
    int c = l16 & 3;
#pragma unroll
    for (int nt = 0; nt < 4; ++nt){
      int col = n0 + nbase + nt*16 + l16;
      int o = col & 1023, h = o >> 6, d = o & 63;
      int g = d >> 2;
      int ax = g % 3;
      int mask = ax + 1;
      int tbl = (ax == 0) ? 0xA : (ax == 1 ? 0x6 : 0xC);   // '+' bits by component
      float sgn = ((tbl >> c) & 1) ? 1.f : -1.f;
      float inv = __builtin_amdgcn_exp2f(-(float)g * 0.8304820237218405f); // 10000^(-g/16)
      float bv = bias[col];
#pragma unroll
      for (int mt = 0; mt < 8; ++mt){
        int row0 = m0 + mbase + mt*16 + quad*4;
        int b = row0 >> 11, s0 = row0 & 2047;
        size_t obase = ((size_t)((b*16 + h) * 2048 + s0)) * 64 + d;
#pragma unroll
        for (int r = 0; r < 4; ++r){
          float v = acc[mt][nt][r] + bv;
          float vp = __shfl_xor(v, mask);
          float ang = (float)(s0 + r) * inv;
          float co = __cosf(ang) * sc;
          float si = __sinf(ang) * sc * sgn;
          dst[obase + (size_t)r * 64] = f2bf(co * v + si * vp);
        }
      }
    }
  }
}

// ---------------- GEMM: attn-out * Wo^T -> d_out ----------------
// Proven round-1/2 form: triple buffer, depth-2 prefetch, counted vmcnt(3).
__global__ __launch_bounds__(256)
void gemm_o_kernel(const u16* __restrict__ A, const u16* __restrict__ Bw,
                   const float* __restrict__ bias, void* __restrict__ dout,
                   const int* __restrict__ flag){
  __shared__ u16 sA[3][64 * 32];
  __shared__ u16 sB[3][128 * 32];
  int tid = threadIdx.x, w = tid >> 6, lane = tid & 63, quad = lane >> 4, l16 = lane & 15;
  int n0 = blockIdx.x * 128, m0 = blockIdx.y * 64;

  f32x4 acc[2][4];
#pragma unroll
  for (int i = 0; i < 2; ++i)
#pragma unroll
    for (int j = 0; j < 4; ++j) acc[i][j] = (f32x4){0.f, 0.f, 0.f, 0.f};

  int cp = lane & 3, rl = lane >> 2;
  int gc = (cp ^ ((rl >> 1) & 3)) * 8;
  int xorv = ((l16 >> 1) & 3) * 8;
  int mw = (w & 1) * 32, nw = (w >> 1) * 64;

  auto stage = [&](int k0, int b){
#pragma unroll
    for (int i = 0; i < 3; ++i){
      int ch = w * 3 + i;                 // 12 chunks: 4 sA + 8 sB
      int lr = (ch < 4 ? ch : ch - 4) * 16 + rl;
      int eo = (ch < 4 ? ch : ch - 4) * 512 + lane * 8;
      if (ch < 4) gl_lds16(A  + (size_t)(m0 + lr) * 1024 + k0 + gc, &sA[b][eo]);
      else        gl_lds16(Bw + (size_t)(n0 + lr) * 1024 + k0 + gc, &sB[b][eo]);
    }
  };

  stage(0, 0);
  stage(32, 1);
  asm volatile("s_waitcnt vmcnt(3)" ::: "memory");   // tile 0 landed, tile 1 in flight
  __builtin_amdgcn_s_barrier();

  int bcur = 0, bnxt = 2;
  for (int it = 0; it < 32; ++it){
    if (it < 30) stage((it + 2) * 32, bnxt);
    const u16* cA = sA[bcur];
    const u16* cB = sB[bcur];
    bf16x8 af[2], bfr[4];
#pragma unroll
    for (int mt = 0; mt < 2; ++mt)
      af[mt] = *(const bf16x8*)&cA[(mw + mt*16 + l16) * 32 + (quad*8 ^ xorv)];
#pragma unroll
    for (int nt = 0; nt < 4; ++nt)
      bfr[nt] = *(const bf16x8*)&cB[(nw + nt*16 + l16) * 32 + (quad*8 ^ xorv)];
#pragma unroll
    for (int mt = 0; mt < 2; ++mt)
#pragma unroll
      for (int nt = 0; nt < 4; ++nt)
        acc[mt][nt] = MFMA_BF16(af[mt], bfr[nt], acc[mt][nt]);

    if (it < 30) asm volatile("s_waitcnt vmcnt(3)" ::: "memory");
    else         asm volatile("s_waitcnt vmcnt(0)" ::: "memory");
    __builtin_amdgcn_s_barrier();
    bcur = (bcur == 2) ? 0 : bcur + 1;
    bnxt = (bnxt == 2) ? 0 : bnxt + 1;
  }

  int isbf = *flag;
#pragma unroll
  for (int mt = 0; mt < 2; ++mt){
    int row = m0 + mw + mt*16 + quad*4;
#pragma unroll
    for (int nt = 0; nt < 4; ++nt){
      int col = n0 + nw + nt*16 + l16;
      float bv = bias[col];
#pragma unroll
      for (int r = 0; r < 4; ++r){
        float val = acc[mt][nt][r] + bv;
        size_t addr = (size_t)(row + r) * 1024 + col;
        if (isbf) ((u16*)dout)[addr] = f2bf(val);
        else      ((float*)dout)[addr] = val;
      }
    }
  }
}

// ---------------- flash attention v5: pair-balanced work assignment ----------------
#define SPT 20

__global__ __launch_bounds__(256, 2)
void attn_kernel(const u16* __restrict__ Q, const u16* __restrict__ K,
                 const u16* __restrict__ Vt, u16* __restrict__ OP,
                 float* __restrict__ LP){
  __shared__ u16 sK[2][4096];
  __shared__ u16 sPT[4][64 * SPT];
  int bh  = blockIdx.x;
  int spl = blockIdx.y;
  int tid = threadIdx.x, w = tid >> 6, lane = tid & 63, quad = lane >> 4, l16 = lane & 15;
  size_t kbase = (size_t)bh * 2048 * 64;
  size_t vbase = (size_t)bh * 64 * 2048;
  u16* spw = &sPT[w][0];

  auto stage = [&](int kt, int b){
    int kcol = kt * 64;
#pragma unroll
    for (int p = 0; p < 2; ++p){
      int slot = w*128 + p*64 + lane;
      int row = slot >> 3, dc = (slot & 7) ^ (row & 7);
      gl_lds16(K + kbase + (size_t)(kcol + row) * 64 + dc*8, &sK[b][(w*128 + p*64) * 8]);
    }
  };

  for (int item = 0; item < 2; ++item){
    int qt = item ? (int)blockIdx.z : 15 - (int)blockIdx.z;
    int rowbase = qt * 128 + w * 32;

    bf16x8 qf[2][2];
#pragma unroll
    for (int g = 0; g < 2; ++g)
#pragma unroll
      for (int kc = 0; kc < 2; ++kc)
        qf[g][kc] = *(const bf16x8*)(Q + kbase + (size_t)(rowbase + g*16 + l16) * 64 + kc*32 + quad*8);

    f32x4 oaccT[2][4];
    float lsum[2][4];
#pragma unroll
    for (int g = 0; g < 2; ++g)
#pragma unroll
      for (int i = 0; i < 4; ++i){ oaccT[g][i] = (f32x4){0.f,0.f,0.f,0.f}; lsum[g][i] = 0.f; }

    int kt0 = spl ? (qt + 1) : 0;
    int ntiles = qt + 1;

    stage(kt0, 0);
    for (int i = 0; i < ntiles; ++i){
      int kcol = (kt0 + i) * 64;
      __syncthreads();
      if (i + 1 < ntiles) stage(kt0 + i + 1, (i + 1) & 1);
      const u16* bK = sK[i & 1];

      if (kcol <= rowbase + 31){
        bf16x8 vf[4][2];
#pragma unroll
        for (int dn = 0; dn < 4; ++dn)
#pragma unroll
          for (int kc = 0; kc < 2; ++kc)
            vf[dn][kc] = *(const bf16x8*)(Vt + vbase + (size_t)(dn*16 + l16) * 2048
                                          + kcol + kc*32 + quad*8);
        bf16x8 bk[2][4];
#pragma unroll
        for (int kc = 0; kc < 2; ++kc)
#pragma unroll
          for (int nt = 0; nt < 4; ++nt){
            int rw = nt*16 + l16;
            int ch = ((kc*4 + quad) ^ (rw & 7)) * 8;
            bk[kc][nt] = *(const bf16x8*)&bK[rw*64 + ch];
          }
#pragma unroll
        for (int g = 0; g < 2; ++g){
          int G0 = rowbase + g*16;
          if (kcol <= G0 + 15){
            f32x4 sacc[4];
#pragma unroll
            for (int nt = 0; nt < 4; ++nt) sacc[nt] = (f32x4){0.f,0.f,0.f,0.f};
#pragma unroll
            for (int kc = 0; kc < 2; ++kc)
#pragma unroll
              for (int nt = 0; nt < 4; ++nt)
                sacc[nt] = MFMA_BF16(qf[g][kc], bk[kc][nt], sacc[nt]);

            if (kcol + 63 > G0){
#pragma unroll
              for (int nt = 0; nt < 4; ++nt){
                int col = kcol + nt*16 + l16;
                ushort4 pv;
#pragma unroll
                for (int r = 0; r < 4; ++r){
                  int row = G0 + quad*4 + r;
                  float pp = (col <= row) ? __builtin_amdgcn_exp2f(sacc[nt][r]) : 0.f;
                  lsum[g][r] += pp;
                  ((u16*)&pv)[r] = f2bf(pp);
                }
                *(ushort4*)&spw[(nt*16 + l16) * SPT + quad*4] = pv;
              }
            } else {
#pragma unroll
              for (int nt = 0; nt < 4; ++nt){
                ushort4 pv;
#pragma unroll
                for (int r = 0; r < 4; ++r){
                  float pp = __builtin_amdgcn_exp2f(sacc[nt][r]);
                  lsum[g][r] += pp;
                  ((u16*)&pv)[r] = f2bf(pp);
                }
                *(ushort4*)&spw[(nt*16 + l16) * SPT + quad*4] = pv;
              }
            }
#pragma unroll
            for (int kc = 0; kc < 2; ++kc){
              bf16x8 pf;
#pragma unroll
              for (int j = 0; j < 8; ++j)
                pf[j] = ((const __bf16*)spw)[(kc*32 + quad*8 + j) * SPT + l16];
#pragma unroll
              for (int dn = 0; dn < 4; ++dn)
                oaccT[g][dn] = MFMA_BF16(vf[dn][kc], pf, oaccT[g][dn]);
            }
          }
        }
      }
    }

    float* scr = (float*)spw;
#pragma unroll
    for (int g = 0; g < 2; ++g)
#pragma unroll
      for (int r = 0; r < 4; ++r){
        float l = lsum[g][r];
        l += __shfl_xor(l, 1); l += __shfl_xor(l, 2);
        l += __shfl_xor(l, 4); l += __shfl_xor(l, 8);
        if (l16 == 0) scr[g*16 + quad*4 + r] = l;
      }
    float lrow[2];
#pragma unroll
    for (int g = 0; g < 2; ++g) lrow[g] = scr[g*16 + l16];

    size_t obase = ((size_t)(spl*32 + bh)) * 2048;
#pragma unroll
    for (int g = 0; g < 2; ++g){
      int row = rowbase + g*16 + l16;
      if (quad == 0) LP[obase + row] = lrow[g];
#pragma unroll
      for (int dn = 0; dn < 4; ++dn){
        ushort4 ov = { f2bf(oaccT[g][dn][0]), f2bf(oaccT[g][dn][1]),
                       f2bf(oaccT[g][dn][2]), f2bf(oaccT[g][dn][3]) };
        *(ushort4*)&OP[(obase + row) * 64 + dn*16 + quad*4] = ov;
      }
    }

    // protect sK / sPT reuse before the second item's staging begins
    __syncthreads();
  }
}

// ---------------- combine splits -> Ab (b, s, h*64+d) bf16 ----------------
__global__ void combine_kernel(const u16* __restrict__ OP, const float* __restrict__ LP,
                               u16* __restrict__ Ab){
  int idx = blockIdx.x * 256 + threadIdx.x;
  int dc = idx & 7, s = (idx >> 3) & 2047, bh = idx >> 14;
  size_t r0 = (size_t)bh * 2048 + s, r1 = (size_t)(32 + bh) * 2048 + s;
  float invl = 1.f / (LP[r0] + LP[r1]);
  union { uint4 v; u16 h[8]; } a0, a1; ushort4 o[2];
  a0.v = *(const uint4*)&OP[r0 * 64 + dc*8];
  a1.v = *(const uint4*)&OP[r1 * 64 + dc*8];
#pragma unroll
  for (int p = 0; p < 2; ++p)
#pragma unroll
    for (int j = 0; j < 4; ++j)
      ((u16*)&o[p])[j] = f2bf((bf2f(a0.h[p*4+j]) + bf2f(a1.h[p*4+j])) * invl);
  int b = bh >> 4, h = bh & 15;
  u16* dst = &Ab[((size_t)(b*2048 + s)) * 1024 + h*64 + dc*8];
  *(ushort4*)dst = o[0];
  *(ushort4*)(dst + 4) = o[1];
}

// ---------------- launcher ----------------
extern "C" void kernel_launch(void* const* d_in, const int* in_sizes, int n_in,
                              void* d_out, int out_size, void* d_ws, size_t ws_size,
                              hipStream_t stream){
  (void)in_sizes; (void)n_in; (void)out_size; (void)ws_size;
  char* ws = (char*)d_ws;
  int*   flag  = (int*)ws;
  u16*   Xbf   = (u16*)(ws + XBF_OFF);
  u16*   Wd    = (u16*)(ws + WD_OFF);
  float* biasf = (float*)(ws + BIAS_OFF);
  u16*   Qb    = (u16*)(ws + QB_OFF);
  u16*   Kb    = (u16*)(ws + KB_OFF);
  u16*   Vt    = (u16*)(ws + VT_OFF);
  u16*   OP    = (u16*)(ws + OP_OFF);
  float* LP    = (float*)(ws + LP_OFF);
  u16*   Ab    = Xbf;

  QPtrs ptrs;
  for (int p = 0; p < 4; ++p){
    for (int wi = 0; wi < 4; ++wi) ptrs.w[p*4 + wi] = d_in[2 + p*5 + wi];
    ptrs.b[p] = d_in[2 + p*5 + 4];
  }

  prep_kernel<<<4096, 256, 0, stream>>>(d_in[0], ptrs, Xbf, Wd, biasf, flag);
  gemm_qkv_kernel<<<dim3(12, 16), 512, 0, stream>>>(Xbf, Wd, biasf, Qb, Kb, Vt);
  attn_kernel<<<dim3(32, 2, 8), 256, 0, stream>>>(Qb, Kb, Vt, OP, LP);
  combine_kernel<<<2048, 256, 0, stream>>>(OP, LP, Ab);
  gemm_o_kernel<<<dim3(8, 64), 256, 0, stream>>>(Ab, Wd + 3*1048576, biasf + 3072,
                                                 d_out, flag);
}